// Round 8
// baseline (233.765 us; speedup 1.0000x reference)
//
#include <hip/hip_runtime.h>
#include <math.h>

#define C 512
#define NPIX 4096   // 64*64
#define BATCH 16
#define O 512
#define R 6
#define LN_EPS 1e-5f

typedef float vf2 __attribute__((ext_vector_type(2)));

// ws layout (floats):
// [0, 4096)     wpsiT[c*8 + r] = ln_w[c]*psi[r,c]   (r<6; pads 6,7 unused)
// [4096, 4104)  swp[r] = sum_c ln_w[c]*psi[r,c]
// [4104, 4112)  sbp[r] = sum_c ln_b[c]*psi[r,c]
// [4112, 8208)  M[o*8 + r] = sum_c psi[r,c]*fc_w[o,c] + fc_b[o]  (pads 6,7 unused)

__device__ __forceinline__ void hermite_rows(int c, float rows[R]) {
    float t = -1.0f + 2.0f * (float)c / 511.0f;
    float xd = tanhf(t) * 4.31662479035539984911f;  // sqrt(11)+1
    float g = expf(-0.5f * xd * xd);
    const float pi_m14 = 0.75112554446494248286f;   // pi^-0.25
    rows[0] = pi_m14 * g;
    rows[1] = 1.41421356237309504880f * pi_m14 * xd * g;
    #pragma unroll
    for (int k = 2; k <= 5; ++k)
        rows[k] = sqrtf(2.0f / k) * xd * rows[k - 1] - sqrtf((k - 1.0f) / k) * rows[k - 2];
}

// One dispatch for ALL setup. Blocks 0..511: M row o (recompute psi locally).
// Block 512: wpsiT + swp/sbp.
__global__ __launch_bounds__(64) void setup_all(const float* __restrict__ lnw,
                                                const float* __restrict__ lnb,
                                                const float* __restrict__ fcw,
                                                const float* __restrict__ fcb,
                                                float* __restrict__ ws) {
    const int o = blockIdx.x;
    const int l = threadIdx.x;
    if (o < O) {
        float acc[R] = {0.f, 0.f, 0.f, 0.f, 0.f, 0.f};
        #pragma unroll
        for (int k = 0; k < 8; ++k) {
            int c = l + (k << 6);
            float rows[R];
            hermite_rows(c, rows);
            float w = fcw[o * C + c];
            #pragma unroll
            for (int r = 0; r < R; ++r) acc[r] += rows[r] * w;
        }
        #pragma unroll
        for (int r = 0; r < R; ++r)
            #pragma unroll
            for (int m = 32; m >= 1; m >>= 1) acc[r] += __shfl_xor(acc[r], m, 64);
        if (l == 0) {
            float bias = fcb[o];   // softmax weights sum to 1 -> fold bias into M
            float* M = ws + 4112 + o * 8;
            #pragma unroll
            for (int r = 0; r < R; ++r) M[r] = acc[r] + bias;
        }
    } else {
        float sw[R] = {0.f, 0.f, 0.f, 0.f, 0.f, 0.f};
        float sb[R] = {0.f, 0.f, 0.f, 0.f, 0.f, 0.f};
        #pragma unroll
        for (int k = 0; k < 8; ++k) {
            int c = l + (k << 6);
            float rows[R];
            hermite_rows(c, rows);
            float w = lnw[c], bb = lnb[c];
            float* dst = ws + c * 8;
            #pragma unroll
            for (int r = 0; r < R; ++r) {
                float rw = rows[r] * w;
                dst[r] = rw;
                sw[r] += rw;
                sb[r] += rows[r] * bb;
            }
        }
        #pragma unroll
        for (int r = 0; r < R; ++r) {
            #pragma unroll
            for (int m = 32; m >= 1; m >>= 1) {
                sw[r] += __shfl_xor(sw[r], m, 64);
                sb[r] += __shfl_xor(sb[r], m, 64);
            }
        }
        if (l == 0) {
            #pragma unroll
            for (int r = 0; r < R; ++r) { ws[4096 + r] = sw[r]; ws[4104 + r] = sb[r]; }
        }
    }
}

// Fused, R/W-overlapped, all-nontemporal. 256 blocks (16 b x 16 tiles of
// 256 px) x 1024 threads (16 waves, 32 ch / 32 o-rows each). Tile = two
// 128-px halves A,B. Epochs:
//   [read A (nt)] [combine A]
//   [MIDDLE: per 8-chunk — issue 8 nt loads of B, then 8 nt stores of A,
//    then consume the loads. In-order vmcnt: the consume only waits on the
//    oldest entries (the loads); the younger stores drain under the next
//    chunk's reads. sched_barrier(0) pins issue order. This is bulk-chunk
//    separation — NOT r4's 1:1 coupling.]
//   [combine B] [write B (nt)]
// Tile-A's 10us of stores hide under tile-B's reads; both memory
// directions are in flight, which the 6.3 TB/s copy ubench proves the
// fabric sustains.
__global__ __launch_bounds__(1024, 4) void fused_kernel(const float* __restrict__ x,
                                                        const float* __restrict__ ws,
                                                        float* __restrict__ out) {
    __shared__ float part[16][8][128];  // [wave][stat][px], 64 KB
    __shared__ float attn_s[R][128];    // 3 KB
    const int tid = threadIdx.x;
    const int wv = tid >> 6;
    const int l = tid & 63;
    const int b = blockIdx.x >> 4;
    const int grp = blockIdx.x & 15;
    const int n0 = grp << 8;            // 256-px tile; halves at n0, n0+128
    const int p2 = l << 1;
    const int wuni = __builtin_amdgcn_readfirstlane(wv);  // force SGPR

    const float* xw = x + (((size_t)(b * C + (wuni << 5))) << 12);
    float* ow = out + (((size_t)(b * O + (wuni << 5))) << 12);
    const float* wbase = ws + ((size_t)(wuni << 5) << 3);
    const float* Ms = ws + 4112 + ((size_t)(wuni << 5) << 3);

    float sx, sy, ssx, ssy;
    float a0x, a0y, a1x, a1y, a2x, a2y, a3x, a3y, a4x, a4y, a5x, a5y;
    float arx[R], ary[R];

    // ================= epoch 1: read half A (nt) =================
    {
        const float* xb = xw + n0 + p2;
        sx = sy = ssx = ssy = 0.f;
        a0x = a0y = a1x = a1y = a2x = a2y = 0.f;
        a3x = a3y = a4x = a4y = a5x = a5y = 0.f;
        #pragma unroll
        for (int i = 0; i < 32; ++i) {
            vf2 xv = __builtin_nontemporal_load((const vf2*)(xb + ((size_t)i << 12)));
            const float* wr = wbase + (i << 3);     // wave-uniform -> s_load
            float w0 = wr[0], w1 = wr[1], w2 = wr[2];
            float w3 = wr[3], w4 = wr[4], w5 = wr[5];
            sx += xv.x;          sy += xv.y;
            ssx += xv.x * xv.x;  ssy += xv.y * xv.y;
            a0x += xv.x * w0;    a0y += xv.y * w0;
            a1x += xv.x * w1;    a1y += xv.y * w1;
            a2x += xv.x * w2;    a2y += xv.y * w2;
            a3x += xv.x * w3;    a3y += xv.y * w3;
            a4x += xv.x * w4;    a4y += xv.y * w4;
            a5x += xv.x * w5;    a5y += xv.y * w5;
        }
        vf2 t;
        t.x = sx;  t.y = sy;  *(vf2*)&part[wv][0][p2] = t;
        t.x = ssx; t.y = ssy; *(vf2*)&part[wv][1][p2] = t;
        t.x = a0x; t.y = a0y; *(vf2*)&part[wv][2][p2] = t;
        t.x = a1x; t.y = a1y; *(vf2*)&part[wv][3][p2] = t;
        t.x = a2x; t.y = a2y; *(vf2*)&part[wv][4][p2] = t;
        t.x = a3x; t.y = a3y; *(vf2*)&part[wv][5][p2] = t;
        t.x = a4x; t.y = a4y; *(vf2*)&part[wv][6][p2] = t;
        t.x = a5x; t.y = a5y; *(vf2*)&part[wv][7][p2] = t;
    }
    __syncthreads();

    // ---- combine + softmax A ----
    if (tid < 128) {
        float v[8];
        #pragma unroll
        for (int st = 0; st < 8; ++st) {
            float acc = 0.f;
            #pragma unroll
            for (int w = 0; w < 16; ++w) acc += part[w][st][tid];
            v[st] = acc;
        }
        float mu = v[0] * (1.0f / 512.0f);
        float var = v[1] * (1.0f / 512.0f) - mu * mu;
        float rsig = rsqrtf(var + LN_EPS);
        const float invsq = 0.04419417382415922f;  // 1/sqrt(512)
        float sc[R], mx = -1e30f;
        #pragma unroll
        for (int r = 0; r < R; ++r) {
            float swp = ws[4096 + r], sbp = ws[4104 + r];
            sc[r] = ((v[2 + r] - mu * swp) * rsig + sbp) * invsq;
            mx = fmaxf(mx, sc[r]);
        }
        float es = 0.f, at[R];
        #pragma unroll
        for (int r = 0; r < R; ++r) { at[r] = expf(sc[r] - mx); es += at[r]; }
        float inv = 1.0f / es;
        #pragma unroll
        for (int r = 0; r < R; ++r) attn_s[r][tid] = at[r] * inv;
    }
    __syncthreads();

    #pragma unroll
    for (int r = 0; r < R; ++r) {
        vf2 a = *(const vf2*)&attn_s[r][p2];
        arx[r] = a.x; ary[r] = a.y;
    }

    // ===== epoch 2 (middle): read B in 8-chunks, stores of A in the shadow =====
    {
        const float* xb = xw + n0 + 128 + p2;
        float* ob = ow + n0 + p2;
        sx = sy = ssx = ssy = 0.f;
        a0x = a0y = a1x = a1y = a2x = a2y = 0.f;
        a3x = a3y = a4x = a4y = a5x = a5y = 0.f;
        for (int k = 0; k < 4; ++k) {
            vf2 xv[8];
            #pragma unroll
            for (int j = 0; j < 8; ++j)
                xv[j] = __builtin_nontemporal_load(
                    (const vf2*)(xb + ((size_t)((k << 3) + j) << 12)));
            __builtin_amdgcn_sched_barrier(0);
            #pragma unroll
            for (int j = 0; j < 8; ++j) {
                const float* mo = Ms + (((k << 3) + j) << 3);  // uniform s_load
                float m0 = mo[0], m1 = mo[1], m2 = mo[2];
                float m3 = mo[3], m4 = mo[4], m5 = mo[5];
                vf2 res;
                res.x = arx[0] * m0 + arx[1] * m1 + arx[2] * m2
                      + arx[3] * m3 + arx[4] * m4 + arx[5] * m5;
                res.y = ary[0] * m0 + ary[1] * m1 + ary[2] * m2
                      + ary[3] * m3 + ary[4] * m4 + ary[5] * m5;
                __builtin_nontemporal_store(res, (vf2*)(ob + ((size_t)((k << 3) + j) << 12)));
            }
            __builtin_amdgcn_sched_barrier(0);
            #pragma unroll
            for (int j = 0; j < 8; ++j) {
                const float* wr = wbase + (((k << 3) + j) << 3);
                float w0 = wr[0], w1 = wr[1], w2 = wr[2];
                float w3 = wr[3], w4 = wr[4], w5 = wr[5];
                vf2 xv_ = xv[j];
                sx += xv_.x;          sy += xv_.y;
                ssx += xv_.x * xv_.x; ssy += xv_.y * xv_.y;
                a0x += xv_.x * w0;    a0y += xv_.y * w0;
                a1x += xv_.x * w1;    a1y += xv_.y * w1;
                a2x += xv_.x * w2;    a2y += xv_.y * w2;
                a3x += xv_.x * w3;    a3y += xv_.y * w3;
                a4x += xv_.x * w4;    a4y += xv_.y * w4;
                a5x += xv_.x * w5;    a5y += xv_.y * w5;
            }
        }
        vf2 t;
        t.x = sx;  t.y = sy;  *(vf2*)&part[wv][0][p2] = t;
        t.x = ssx; t.y = ssy; *(vf2*)&part[wv][1][p2] = t;
        t.x = a0x; t.y = a0y; *(vf2*)&part[wv][2][p2] = t;
        t.x = a1x; t.y = a1y; *(vf2*)&part[wv][3][p2] = t;
        t.x = a2x; t.y = a2y; *(vf2*)&part[wv][4][p2] = t;
        t.x = a3x; t.y = a3y; *(vf2*)&part[wv][5][p2] = t;
        t.x = a4x; t.y = a4y; *(vf2*)&part[wv][6][p2] = t;
        t.x = a5x; t.y = a5y; *(vf2*)&part[wv][7][p2] = t;
    }
    __syncthreads();

    // ---- combine + softmax B ----
    if (tid < 128) {
        float v[8];
        #pragma unroll
        for (int st = 0; st < 8; ++st) {
            float acc = 0.f;
            #pragma unroll
            for (int w = 0; w < 16; ++w) acc += part[w][st][tid];
            v[st] = acc;
        }
        float mu = v[0] * (1.0f / 512.0f);
        float var = v[1] * (1.0f / 512.0f) - mu * mu;
        float rsig = rsqrtf(var + LN_EPS);
        const float invsq = 0.04419417382415922f;  // 1/sqrt(512)
        float sc[R], mx = -1e30f;
        #pragma unroll
        for (int r = 0; r < R; ++r) {
            float swp = ws[4096 + r], sbp = ws[4104 + r];
            sc[r] = ((v[2 + r] - mu * swp) * rsig + sbp) * invsq;
            mx = fmaxf(mx, sc[r]);
        }
        float es = 0.f, at[R];
        #pragma unroll
        for (int r = 0; r < R; ++r) { at[r] = expf(sc[r] - mx); es += at[r]; }
        float inv = 1.0f / es;
        #pragma unroll
        for (int r = 0; r < R; ++r) attn_s[r][tid] = at[r] * inv;
    }
    __syncthreads();

    #pragma unroll
    for (int r = 0; r < R; ++r) {
        vf2 a = *(const vf2*)&attn_s[r][p2];
        arx[r] = a.x; ary[r] = a.y;
    }

    // ================= epoch 3: write half B (nt) =================
    {
        float* ob = ow + n0 + 128 + p2;
        #pragma unroll
        for (int j = 0; j < 32; ++j) {
            const float* mo = Ms + (j << 3);        // wave-uniform -> s_load
            float m0 = mo[0], m1 = mo[1], m2 = mo[2];
            float m3 = mo[3], m4 = mo[4], m5 = mo[5];
            vf2 res;
            res.x = arx[0] * m0 + arx[1] * m1 + arx[2] * m2
                  + arx[3] * m3 + arx[4] * m4 + arx[5] * m5;
            res.y = ary[0] * m0 + ary[1] * m1 + ary[2] * m2
                  + ary[3] * m3 + ary[4] * m4 + ary[5] * m5;
            __builtin_nontemporal_store(res, (vf2*)(ob + ((size_t)j << 12)));
        }
    }
}

extern "C" void kernel_launch(void* const* d_in, const int* in_sizes, int n_in,
                              void* d_out, int out_size, void* d_ws, size_t ws_size,
                              hipStream_t stream) {
    const float* x    = (const float*)d_in[0];
    const float* ln_w = (const float*)d_in[1];
    const float* ln_b = (const float*)d_in[2];
    const float* fc_w = (const float*)d_in[3];
    const float* fc_b = (const float*)d_in[4];
    float* out = (float*)d_out;
    float* ws = (float*)d_ws;

    setup_all<<<O + 1, 64, 0, stream>>>(ln_w, ln_b, fc_w, fc_b, ws);
    fused_kernel<<<BATCH * 16, 1024, 0, stream>>>(x, ws, out);
}

// Round 9
// 231.329 us; speedup vs baseline: 1.0105x; 1.0105x over previous
//
#include <hip/hip_runtime.h>
#include <math.h>

#define C 512
#define NPIX 4096   // 64*64
#define BATCH 16
#define O 512
#define R 6
#define LN_EPS 1e-5f

typedef float vf2 __attribute__((ext_vector_type(2)));

// ws layout (floats):
// [0, 4096)     wpsiT[c*8 + r] = ln_w[c]*psi[r,c]   (r<6; pads 6,7 unused)
// [4096, 4104)  swp[r] = sum_c ln_w[c]*psi[r,c]
// [4104, 4112)  sbp[r] = sum_c ln_b[c]*psi[r,c]
// [4112, 8208)  M[o*8 + r] = sum_c psi[r,c]*fc_w[o,c] + fc_b[o]  (pads 6,7 unused)

__device__ __forceinline__ void hermite_rows(int c, float rows[R]) {
    float t = -1.0f + 2.0f * (float)c / 511.0f;
    float xd = tanhf(t) * 4.31662479035539984911f;  // sqrt(11)+1
    float g = expf(-0.5f * xd * xd);
    const float pi_m14 = 0.75112554446494248286f;   // pi^-0.25
    rows[0] = pi_m14 * g;
    rows[1] = 1.41421356237309504880f * pi_m14 * xd * g;
    #pragma unroll
    for (int k = 2; k <= 5; ++k)
        rows[k] = sqrtf(2.0f / k) * xd * rows[k - 1] - sqrtf((k - 1.0f) / k) * rows[k - 2];
}

// One dispatch for ALL setup. Blocks 0..511: M row o (recompute psi locally).
// Block 512: wpsiT + swp/sbp.
__global__ __launch_bounds__(64) void setup_all(const float* __restrict__ lnw,
                                                const float* __restrict__ lnb,
                                                const float* __restrict__ fcw,
                                                const float* __restrict__ fcb,
                                                float* __restrict__ ws) {
    const int o = blockIdx.x;
    const int l = threadIdx.x;
    if (o < O) {
        float acc[R] = {0.f, 0.f, 0.f, 0.f, 0.f, 0.f};
        #pragma unroll
        for (int k = 0; k < 8; ++k) {
            int c = l + (k << 6);
            float rows[R];
            hermite_rows(c, rows);
            float w = fcw[o * C + c];
            #pragma unroll
            for (int r = 0; r < R; ++r) acc[r] += rows[r] * w;
        }
        #pragma unroll
        for (int r = 0; r < R; ++r)
            #pragma unroll
            for (int m = 32; m >= 1; m >>= 1) acc[r] += __shfl_xor(acc[r], m, 64);
        if (l == 0) {
            float bias = fcb[o];   // softmax weights sum to 1 -> fold bias into M
            float* M = ws + 4112 + o * 8;
            #pragma unroll
            for (int r = 0; r < R; ++r) M[r] = acc[r] + bias;
        }
    } else {
        float sw[R] = {0.f, 0.f, 0.f, 0.f, 0.f, 0.f};
        float sb[R] = {0.f, 0.f, 0.f, 0.f, 0.f, 0.f};
        #pragma unroll
        for (int k = 0; k < 8; ++k) {
            int c = l + (k << 6);
            float rows[R];
            hermite_rows(c, rows);
            float w = lnw[c], bb = lnb[c];
            float* dst = ws + c * 8;
            #pragma unroll
            for (int r = 0; r < R; ++r) {
                float rw = rows[r] * w;
                dst[r] = rw;
                sw[r] += rw;
                sb[r] += rows[r] * bb;
            }
        }
        #pragma unroll
        for (int r = 0; r < R; ++r) {
            #pragma unroll
            for (int m = 32; m >= 1; m >>= 1) {
                sw[r] += __shfl_xor(sw[r], m, 64);
                sb[r] += __shfl_xor(sb[r], m, 64);
            }
        }
        if (l == 0) {
            #pragma unroll
            for (int r = 0; r < R; ++r) { ws[4096 + r] = sw[r]; ws[4104 + r] = sb[r]; }
        }
    }
}

// Fused, WAVE-ROLE-SPLIT R/W overlap. 256 blocks (16 b x 16 supertiles of
// 256 px) x 1024 threads (16 waves). Each block owns two 128-px tiles A,B.
//   S1: ALL 16 waves read A (32 ch each, nt).            [pure read]
//   combine+softmax A -> attn[0]
//   S2: waves 0-7 read B (64 ch each, nt)  ||  waves 8-15 write A
//       (64 o-rows each, nt).  DIFFERENT waves carry the read and write
//       streams -> no shared vmcnt queue, no instruction interleave; the
//       CU scheduler co-issues them (m114: separate-wave pipes overlap
//       fully, time = max not sum). This is the overlap mechanism r4/r6/r8
//       (all intra-wave) could not reach.
//   combine+softmax B -> attn[1]
//   S3: ALL 16 waves write B (32 rows each, nt).
__global__ __launch_bounds__(1024, 4) void fused_kernel(const float* __restrict__ x,
                                                        const float* __restrict__ ws,
                                                        float* __restrict__ out) {
    __shared__ float part[16][8][128];  // [wave][stat][px], 64 KB
    __shared__ float attn_s[2][R][128]; // 6 KB (A and B coexist across S2)
    const int tid = threadIdx.x;
    const int wv = tid >> 6;
    const int l = tid & 63;
    const int b = blockIdx.x >> 4;
    const int st = blockIdx.x & 15;
    const int nA = st << 8;             // tile A px base
    const int nB = nA + 128;            // tile B px base
    const int p2 = l << 1;
    const int wuni = __builtin_amdgcn_readfirstlane(wv);  // force SGPR

    const float* xrow = x + (((size_t)(b * C)) << 12);
    float* orow = out + (((size_t)(b * O)) << 12);

    float sx, sy, ssx, ssy;
    float a0x, a0y, a1x, a1y, a2x, a2y, a3x, a3y, a4x, a4y, a5x, a5y;

    // ================= S1: all 16 waves read tile A (32 ch each) =============
    {
        const float* xb = xrow + (((size_t)(wuni << 5)) << 12) + nA + p2;
        const float* wbase = ws + ((size_t)(wuni << 5) << 3);
        sx = sy = ssx = ssy = 0.f;
        a0x = a0y = a1x = a1y = a2x = a2y = 0.f;
        a3x = a3y = a4x = a4y = a5x = a5y = 0.f;
        #pragma unroll
        for (int i = 0; i < 32; ++i) {
            vf2 xv = __builtin_nontemporal_load((const vf2*)(xb + ((size_t)i << 12)));
            const float* wr = wbase + (i << 3);     // wave-uniform -> s_load
            float w0 = wr[0], w1 = wr[1], w2 = wr[2];
            float w3 = wr[3], w4 = wr[4], w5 = wr[5];
            sx += xv.x;          sy += xv.y;
            ssx += xv.x * xv.x;  ssy += xv.y * xv.y;
            a0x += xv.x * w0;    a0y += xv.y * w0;
            a1x += xv.x * w1;    a1y += xv.y * w1;
            a2x += xv.x * w2;    a2y += xv.y * w2;
            a3x += xv.x * w3;    a3y += xv.y * w3;
            a4x += xv.x * w4;    a4y += xv.y * w4;
            a5x += xv.x * w5;    a5y += xv.y * w5;
        }
        vf2 t;
        t.x = sx;  t.y = sy;  *(vf2*)&part[wv][0][p2] = t;
        t.x = ssx; t.y = ssy; *(vf2*)&part[wv][1][p2] = t;
        t.x = a0x; t.y = a0y; *(vf2*)&part[wv][2][p2] = t;
        t.x = a1x; t.y = a1y; *(vf2*)&part[wv][3][p2] = t;
        t.x = a2x; t.y = a2y; *(vf2*)&part[wv][4][p2] = t;
        t.x = a3x; t.y = a3y; *(vf2*)&part[wv][5][p2] = t;
        t.x = a4x; t.y = a4y; *(vf2*)&part[wv][6][p2] = t;
        t.x = a5x; t.y = a5y; *(vf2*)&part[wv][7][p2] = t;
    }
    __syncthreads();

    // ---- combine + softmax A -> attn_s[0] (sums 16 wave-partials) ----
    if (tid < 128) {
        float v[8];
        #pragma unroll
        for (int s = 0; s < 8; ++s) {
            float acc = 0.f;
            #pragma unroll
            for (int w = 0; w < 16; ++w) acc += part[w][s][tid];
            v[s] = acc;
        }
        float mu = v[0] * (1.0f / 512.0f);
        float var = v[1] * (1.0f / 512.0f) - mu * mu;
        float rsig = rsqrtf(var + LN_EPS);
        const float invsq = 0.04419417382415922f;  // 1/sqrt(512)
        float sc[R], mx = -1e30f;
        #pragma unroll
        for (int r = 0; r < R; ++r) {
            float swp = ws[4096 + r], sbp = ws[4104 + r];
            sc[r] = ((v[2 + r] - mu * swp) * rsig + sbp) * invsq;
            mx = fmaxf(mx, sc[r]);
        }
        float es = 0.f, at[R];
        #pragma unroll
        for (int r = 0; r < R; ++r) { at[r] = expf(sc[r] - mx); es += at[r]; }
        float inv = 1.0f / es;
        #pragma unroll
        for (int r = 0; r < R; ++r) attn_s[0][r][tid] = at[r] * inv;
    }
    __syncthreads();

    // ===== S2: waves 0-7 read tile B  ||  waves 8-15 write tile A =====
    if (wv < 8) {
        // R-waves: 64 channels each, tile B.
        const float* xb = xrow + (((size_t)(wuni << 6)) << 12) + nB + p2;
        const float* wbase = ws + ((size_t)(wuni << 6) << 3);
        sx = sy = ssx = ssy = 0.f;
        a0x = a0y = a1x = a1y = a2x = a2y = 0.f;
        a3x = a3y = a4x = a4y = a5x = a5y = 0.f;
        #pragma unroll 8
        for (int i = 0; i < 64; ++i) {
            vf2 xv = __builtin_nontemporal_load((const vf2*)(xb + ((size_t)i << 12)));
            const float* wr = wbase + (i << 3);
            float w0 = wr[0], w1 = wr[1], w2 = wr[2];
            float w3 = wr[3], w4 = wr[4], w5 = wr[5];
            sx += xv.x;          sy += xv.y;
            ssx += xv.x * xv.x;  ssy += xv.y * xv.y;
            a0x += xv.x * w0;    a0y += xv.y * w0;
            a1x += xv.x * w1;    a1y += xv.y * w1;
            a2x += xv.x * w2;    a2y += xv.y * w2;
            a3x += xv.x * w3;    a3y += xv.y * w3;
            a4x += xv.x * w4;    a4y += xv.y * w4;
            a5x += xv.x * w5;    a5y += xv.y * w5;
        }
        vf2 t;
        t.x = sx;  t.y = sy;  *(vf2*)&part[wv][0][p2] = t;
        t.x = ssx; t.y = ssy; *(vf2*)&part[wv][1][p2] = t;
        t.x = a0x; t.y = a0y; *(vf2*)&part[wv][2][p2] = t;
        t.x = a1x; t.y = a1y; *(vf2*)&part[wv][3][p2] = t;
        t.x = a2x; t.y = a2y; *(vf2*)&part[wv][4][p2] = t;
        t.x = a3x; t.y = a3y; *(vf2*)&part[wv][5][p2] = t;
        t.x = a4x; t.y = a4y; *(vf2*)&part[wv][6][p2] = t;
        t.x = a5x; t.y = a5y; *(vf2*)&part[wv][7][p2] = t;
    } else {
        // W-waves: 64 o-rows each, tile A, using attn_s[0].
        float arx[R], ary[R];
        #pragma unroll
        for (int r = 0; r < R; ++r) {
            vf2 a = *(const vf2*)&attn_s[0][r][p2];
            arx[r] = a.x; ary[r] = a.y;
        }
        const int w8 = wuni - 8;
        const float* Ms = ws + 4112 + ((size_t)(w8 << 6) << 3);
        float* ob = orow + (((size_t)(w8 << 6)) << 12) + nA + p2;
        #pragma unroll 8
        for (int j = 0; j < 64; ++j) {
            const float* mo = Ms + (j << 3);
            float m0 = mo[0], m1 = mo[1], m2 = mo[2];
            float m3 = mo[3], m4 = mo[4], m5 = mo[5];
            vf2 res;
            res.x = arx[0] * m0 + arx[1] * m1 + arx[2] * m2
                  + arx[3] * m3 + arx[4] * m4 + arx[5] * m5;
            res.y = ary[0] * m0 + ary[1] * m1 + ary[2] * m2
                  + ary[3] * m3 + ary[4] * m4 + ary[5] * m5;
            __builtin_nontemporal_store(res, (vf2*)(ob + ((size_t)j << 12)));
        }
    }
    __syncthreads();

    // ---- combine + softmax B -> attn_s[1] (sums 8 wave-partials) ----
    if (tid < 128) {
        float v[8];
        #pragma unroll
        for (int s = 0; s < 8; ++s) {
            float acc = 0.f;
            #pragma unroll
            for (int w = 0; w < 8; ++w) acc += part[w][s][tid];
            v[s] = acc;
        }
        float mu = v[0] * (1.0f / 512.0f);
        float var = v[1] * (1.0f / 512.0f) - mu * mu;
        float rsig = rsqrtf(var + LN_EPS);
        const float invsq = 0.04419417382415922f;  // 1/sqrt(512)
        float sc[R], mx = -1e30f;
        #pragma unroll
        for (int r = 0; r < R; ++r) {
            float swp = ws[4096 + r], sbp = ws[4104 + r];
            sc[r] = ((v[2 + r] - mu * swp) * rsig + sbp) * invsq;
            mx = fmaxf(mx, sc[r]);
        }
        float es = 0.f, at[R];
        #pragma unroll
        for (int r = 0; r < R; ++r) { at[r] = expf(sc[r] - mx); es += at[r]; }
        float inv = 1.0f / es;
        #pragma unroll
        for (int r = 0; r < R; ++r) attn_s[1][r][tid] = at[r] * inv;
    }
    __syncthreads();

    // ================= S3: all 16 waves write tile B (32 rows each) ==========
    {
        float arx[R], ary[R];
        #pragma unroll
        for (int r = 0; r < R; ++r) {
            vf2 a = *(const vf2*)&attn_s[1][r][p2];
            arx[r] = a.x; ary[r] = a.y;
        }
        const float* Ms = ws + 4112 + ((size_t)(wuni << 5) << 3);
        float* ob = orow + (((size_t)(wuni << 5)) << 12) + nB + p2;
        #pragma unroll
        for (int j = 0; j < 32; ++j) {
            const float* mo = Ms + (j << 3);
            float m0 = mo[0], m1 = mo[1], m2 = mo[2];
            float m3 = mo[3], m4 = mo[4], m5 = mo[5];
            vf2 res;
            res.x = arx[0] * m0 + arx[1] * m1 + arx[2] * m2
                  + arx[3] * m3 + arx[4] * m4 + arx[5] * m5;
            res.y = ary[0] * m0 + ary[1] * m1 + ary[2] * m2
                  + ary[3] * m3 + ary[4] * m4 + ary[5] * m5;
            __builtin_nontemporal_store(res, (vf2*)(ob + ((size_t)j << 12)));
        }
    }
}

extern "C" void kernel_launch(void* const* d_in, const int* in_sizes, int n_in,
                              void* d_out, int out_size, void* d_ws, size_t ws_size,
                              hipStream_t stream) {
    const float* x    = (const float*)d_in[0];
    const float* ln_w = (const float*)d_in[1];
    const float* ln_b = (const float*)d_in[2];
    const float* fc_w = (const float*)d_in[3];
    const float* fc_b = (const float*)d_in[4];
    float* out = (float*)d_out;
    float* ws = (float*)d_ws;

    setup_all<<<O + 1, 64, 0, stream>>>(ln_w, ln_b, fc_w, fc_b, ws);
    fused_kernel<<<BATCH * 16, 1024, 0, stream>>>(x, ws, out);
}